// Round 16
// baseline (562.064 us; speedup 1.0000x reference)
//
#include <hip/hip_runtime.h>
#include <hip/hip_bf16.h>
#include <math.h>

// Problem constants (from reference)
constexpr int Bv = 8;
constexpr int Nv = 4096;      // H*W = 64*64
constexpr int Cvd = 512;
constexpr int Tt = 77;
constexpr int Dh = 64;
constexpr int MROWS = Bv * Nv;   // 32768
constexpr int KTROWS = Bv * Tt;  // 616

typedef __attribute__((ext_vector_type(8))) short bf16x8;
typedef __attribute__((ext_vector_type(4))) float f32x4;

__device__ __forceinline__ float bfbits2f(short s) {
    unsigned int u = ((unsigned int)(unsigned short)s) << 16;
    return __uint_as_float(u);
}
__device__ __forceinline__ short f2bfbits(float f) {
    __hip_bfloat16 h = __float2bfloat16(f);
    return *reinterpret_cast<short*>(&h);
}

// ---------------------------------------------------------------------------
// async global->LDS, 16B per lane. LDS dest wave-uniform base; HW adds lane*16.
// ---------------------------------------------------------------------------
__device__ __forceinline__ void gload16(const void* g, void* l) {
    __builtin_amdgcn_global_load_lds(
        (const __attribute__((address_space(1))) void*)g,
        (__attribute__((address_space(3))) void*)l, 16, 0, 0);
}

// raw barrier with compiler memory fences (NO vmcnt drain)
__device__ __forceinline__ void block_barrier() {
    asm volatile("" ::: "memory");
    __builtin_amdgcn_s_barrier();
    asm volatile("" ::: "memory");
}

// ---------------------------------------------------------------------------
// All 4 weight transposes in ONE launch: fp32[K,N] -> bf16[N,K].
// ---------------------------------------------------------------------------
__global__ __launch_bounds__(256)
void wtrans4_kernel(const float* __restrict__ Wq, const float* __restrict__ Wo,
                    const float* __restrict__ w1, const float* __restrict__ w2,
                    __hip_bfloat16* __restrict__ WqT, __hip_bfloat16* __restrict__ WoT,
                    __hip_bfloat16* __restrict__ w1T, __hip_bfloat16* __restrict__ w2T)
{
    __shared__ float tile[32][33];
    const int bid = blockIdx.x;
    const float* in;
    __hip_bfloat16* out;
    int K, N, tid;
    if (bid < 256)       { in = Wq; out = WqT; K = 512;  N = 512;  tid = bid; }
    else if (bid < 512)  { in = Wo; out = WoT; K = 512;  N = 512;  tid = bid - 256; }
    else if (bid < 1536) { in = w1; out = w1T; K = 512;  N = 2048; tid = bid - 512; }
    else                 { in = w2; out = w2T; K = 2048; N = 512;  tid = bid - 1536; }
    const int nx = N >> 5;
    const int n0 = (tid % nx) * 32, k0 = (tid / nx) * 32;
    const int tx = threadIdx.x & 31, ty = threadIdx.x >> 5;
    #pragma unroll
    for (int i = ty; i < 32; i += 8)
        tile[i][tx] = in[(size_t)(k0 + i) * N + n0 + tx];
    __syncthreads();
    #pragma unroll
    for (int i = ty; i < 32; i += 8)
        out[(size_t)(n0 + i) * K + k0 + tx] = __float2bfloat16(tile[tx][i]);
}

// ---------------------------------------------------------------------------
// LayerNorm row of 512, 128 threads; writes bf16 (+ optional f32, gate logit)
// ---------------------------------------------------------------------------
template<bool GATE, bool WF32>
__global__ __launch_bounds__(128)
void ln_kernel(const float* __restrict__ in, const float* __restrict__ w,
               const float* __restrict__ b, float* __restrict__ out,
               __hip_bfloat16* __restrict__ out_bf,
               const float* __restrict__ gate_w, const float* __restrict__ gate_b,
               float* __restrict__ gate_out)
{
    __shared__ float red[4];
    __shared__ float redg[2];
    const int row = blockIdx.x;
    const int t = threadIdx.x;
    const int wv = t >> 6;
    const float4 v = ((const float4*)(in + (size_t)row * Cvd))[t];

    float s  = v.x + v.y + v.z + v.w;
    float ss = v.x*v.x + v.y*v.y + v.z*v.z + v.w*v.w;
    #pragma unroll
    for (int o = 1; o < 64; o <<= 1) {
        s  += __shfl_xor(s,  o);
        ss += __shfl_xor(ss, o);
    }
    if ((t & 63) == 0) { red[wv*2] = s; red[wv*2+1] = ss; }
    __syncthreads();
    s  = red[0] + red[2];
    ss = red[1] + red[3];
    const float m   = s * (1.0f / 512.0f);
    const float var = ss * (1.0f / 512.0f) - m * m;
    const float rs  = 1.0f / sqrtf(var + 1e-5f);

    const float4 w4 = ((const float4*)w)[t];
    const float4 b4 = ((const float4*)b)[t];
    float4 o4;
    o4.x = (v.x - m) * rs * w4.x + b4.x;
    o4.y = (v.y - m) * rs * w4.y + b4.y;
    o4.z = (v.z - m) * rs * w4.z + b4.z;
    o4.w = (v.w - m) * rs * w4.w + b4.w;
    if (WF32) ((float4*)(out + (size_t)row * Cvd))[t] = o4;

    __hip_bfloat162 h0, h1;
    h0.x = __float2bfloat16(o4.x); h0.y = __float2bfloat16(o4.y);
    h1.x = __float2bfloat16(o4.z); h1.y = __float2bfloat16(o4.w);
    __hip_bfloat16* obp = out_bf + (size_t)row * Cvd + 4*t;
    *(__hip_bfloat162*)(obp)     = h0;
    *(__hip_bfloat162*)(obp + 2) = h1;

    if (GATE) {
        const float4 g4 = ((const float4*)gate_w)[t];
        float g = o4.x*g4.x + o4.y*g4.y + o4.z*g4.z + o4.w*g4.w;
        #pragma unroll
        for (int o = 1; o < 64; o <<= 1) g += __shfl_xor(g, o);
        if ((t & 63) == 0) redg[wv] = g;
        __syncthreads();
        if (t == 0) {
            const float gt = redg[0] + redg[1] + gate_b[0];
            gate_out[row] = 1.0f / (1.0f + expf(-gt));
        }
    }
}

// ---------------------------------------------------------------------------
// k norm + pad mask + PRE-NORMALIZED bf16 k output (kbf = bf16(k * kinv))
// ---------------------------------------------------------------------------
__global__ __launch_bounds__(64)
void knorm_mask_kernel(const float* __restrict__ kf, const float* __restrict__ text,
                       float* __restrict__ msk, __hip_bfloat16* __restrict__ kbf)
{
    const int row = blockIdx.x;
    const int l = threadIdx.x;
    const float4* rp = (const float4*)(kf + (size_t)row * Cvd);
    const float4* tp = (const float4*)(text + (size_t)row * Cvd);
    const float4 a = rp[l], c = rp[l + 64];
    const float4 ta = tp[l], tc = tp[l + 64];
    float ss = a.x*a.x + a.y*a.y + a.z*a.z + a.w*a.w
             + c.x*c.x + c.y*c.y + c.z*c.z + c.w*c.w;
    float sa = fabsf(ta.x)+fabsf(ta.y)+fabsf(ta.z)+fabsf(ta.w)
             + fabsf(tc.x)+fabsf(tc.y)+fabsf(tc.z)+fabsf(tc.w);
    #pragma unroll
    for (int o = 1; o < 64; o <<= 1) {
        ss += __shfl_xor(ss, o);
        sa += __shfl_xor(sa, o);
    }
    const float ki = 1.0f / fmaxf(sqrtf(ss), 1e-6f);
    if (l == 0) msk[row] = (sa <= 1e-6f) ? 1.0f : 0.0f;

    __hip_bfloat16* kp = kbf + (size_t)row * Cvd;
    __hip_bfloat162 p;
    p.x = __float2bfloat16(a.x * ki); p.y = __float2bfloat16(a.y * ki);
    *(__hip_bfloat162*)(kp + l*4)     = p;
    p.x = __float2bfloat16(a.z * ki); p.y = __float2bfloat16(a.w * ki);
    *(__hip_bfloat162*)(kp + l*4 + 2) = p;
    p.x = __float2bfloat16(c.x * ki); p.y = __float2bfloat16(c.y * ki);
    *(__hip_bfloat162*)(kp + (l+64)*4)     = p;
    p.x = __float2bfloat16(c.z * ki); p.y = __float2bfloat16(c.w * ki);
    *(__hip_bfloat162*)(kp + (l+64)*4 + 2) = p;
}

// ---------------------------------------------------------------------------
// fp32 tiled GEMM for BOTH k and v projections in one launch (blockIdx.z)
// ---------------------------------------------------------------------------
__global__ __launch_bounds__(256)
void gemm32kv_kernel(const float* __restrict__ A,
                     const float* __restrict__ Wk, const float* __restrict__ bk,
                     float* __restrict__ Ck,
                     const float* __restrict__ Wv, const float* __restrict__ bv,
                     float* __restrict__ Cv2,
                     int M, int K)
{
    __shared__ float As[16][64 + 4];
    __shared__ float Bs[16][64 + 4];

    const float* W    = blockIdx.z ? Wv  : Wk;
    const float* bias = blockIdx.z ? bv  : bk;
    float*       C    = blockIdx.z ? Cv2 : Ck;

    const int t = threadIdx.x;
    const int tx = t & 15, ty = t >> 4;
    const int row0 = blockIdx.y * 64;
    const int col0 = blockIdx.x * 64;

    const int arow = t >> 2;
    const int ak   = (t & 3) << 2;
    const int brow = t >> 4;
    const int bcol = (t & 15) << 2;

    float acc[4][4] = {};

    for (int kt = 0; kt < K; kt += 16) {
        float4 a4 = make_float4(0.f, 0.f, 0.f, 0.f);
        const int gr = row0 + arow;
        if (gr < M) a4 = *(const float4*)(A + (size_t)gr * 512 + kt + ak);
        As[ak + 0][arow] = a4.x;
        As[ak + 1][arow] = a4.y;
        As[ak + 2][arow] = a4.z;
        As[ak + 3][arow] = a4.w;
        const float4 b4 = *(const float4*)(W + (size_t)(kt + brow) * 512 + col0 + bcol);
        *(float4*)&Bs[brow][bcol] = b4;
        __syncthreads();
        #pragma unroll
        for (int k = 0; k < 16; k++) {
            const float4 av = *(const float4*)&As[k][ty << 2];
            const float4 bv4 = *(const float4*)&Bs[k][tx << 2];
            acc[0][0] += av.x * bv4.x; acc[0][1] += av.x * bv4.y;
            acc[0][2] += av.x * bv4.z; acc[0][3] += av.x * bv4.w;
            acc[1][0] += av.y * bv4.x; acc[1][1] += av.y * bv4.y;
            acc[1][2] += av.y * bv4.z; acc[1][3] += av.y * bv4.w;
            acc[2][0] += av.z * bv4.x; acc[2][1] += av.z * bv4.y;
            acc[2][2] += av.z * bv4.z; acc[2][3] += av.z * bv4.w;
            acc[3][0] += av.w * bv4.x; acc[3][1] += av.w * bv4.y;
            acc[3][2] += av.w * bv4.z; acc[3][3] += av.w * bv4.w;
        }
        __syncthreads();
    }

    #pragma unroll
    for (int i = 0; i < 4; i++) {
        const int r = row0 + (ty << 2) + i;
        if (r >= M) continue;
        #pragma unroll
        for (int j = 0; j < 4; j++) {
            const int c = col0 + (tx << 2) + j;
            C[(size_t)r * 512 + c] = acc[i][j] + bias[c];
        }
    }
}

// ---------------------------------------------------------------------------
// bf16 MFMA GEMM, 128x128 tile, BK=32, 256 threads (4 waves 2x2).
// Round-11 verified config: ring-3 LDS (48 KiB, 3 blocks/CU), staged 2 ahead,
// counted vmcnt(4), full K-unroll, T2 swizzle. Used for Wq/Wo/FFN2.
// ---------------------------------------------------------------------------
enum { EPI_NONE = 0, EPI_WO = 1, EPI_GELU = 2, EPI_RES = 3, EPI_QBF = 4 };

template<int NT, int EPI>
__global__ __launch_bounds__(256, 3)
void bgemm_kernel(const __hip_bfloat16* __restrict__ Ah,
                  const __hip_bfloat16* __restrict__ Bth,
                  const float* __restrict__ bias,
                  void* __restrict__ Cout,
                  int M, int N,
                  const float* __restrict__ xres,
                  const float* __restrict__ gate,
                  const float* __restrict__ alpha_p,
                  const void* __restrict__ yres)
{
    constexpr int K = NT * 32;
    __shared__ short lds[3 * 8192];   // 48 KiB: 3 bufs x (A 4096 + B 4096 shorts)

    const short* A  = (const short*)Ah;
    const short* Bt = (const short*)Bth;

    // XCD-aware bijective swizzle (nwg % 8 == 0 for all our shapes)
    const int nwg = gridDim.x;
    const int cpx = nwg >> 3;
    const int bid0 = blockIdx.x;
    const int bid = (bid0 & 7) * cpx + (bid0 >> 3);
    const int cols = N >> 7;
    const int row0 = (bid / cols) << 7;
    const int col0 = (bid % cols) << 7;

    const int t = threadIdx.x;
    const int w = t >> 6, l = t & 63;
    const int wr = w >> 1, wc = w & 1;      // 2 x 2 wave grid

    // ---- staging source pointers (lane-fixed); T2 pre-swizzled source ----
    const int src_kelem = (((l & 3) ^ ((l >> 3) & 3)) << 3);
    const short* pA0;
    const short* pA1;
    const short* pB0;
    const short* pB1;
    {
        const int r0 = (2*w)*16 + (l >> 2);
        const int r1 = (2*w + 1)*16 + (l >> 2);
        pA0 = A  + (size_t)(row0 + r0) * K + src_kelem;
        pA1 = A  + (size_t)(row0 + r1) * K + src_kelem;
        pB0 = Bt + (size_t)(col0 + r0) * K + src_kelem;
        pB1 = Bt + (size_t)(col0 + r1) * K + src_kelem;
    }
    short* const dA = lds + (2*w) * 512;   // wave-uniform LDS dests (+ring off)
    short* const dB = lds + 4096 + (2*w) * 512;

    // kt, bW become compile-time constants after full unroll -> imm offsets
    auto STAGE = [&](int kt, int bW) {
        gload16(pA0 + kt * 32, dA + bW * 8192);
        gload16(pA1 + kt * 32, dA + bW * 8192 + 512);
        gload16(pB0 + kt * 32, dB + bW * 8192);
        gload16(pB1 + kt * 32, dB + bW * 8192 + 512);
    };

    // ---- fragment read bases (lane-fixed); per-read offsets all constant ----
    const int axk = (((l >> 4) << 4) ^ (((l >> 1) & 3) << 4));
    const char* const bA = (const char*)lds + (wr*64 + (l & 15))*64 + axk;
    const char* const bB = (const char*)lds + 8192 + (wc*64 + (l & 15))*64 + axk;

    bf16x8 a[4], b[4];
    f32x4 acc[4][4] = {};

    auto RD = [&](int bR) {
        #pragma unroll
        for (int i = 0; i < 4; i++)
            a[i] = *(const bf16x8*)(bA + bR*16384 + i*1024);
        #pragma unroll
        for (int i = 0; i < 4; i++)
            b[i] = *(const bf16x8*)(bB + bR*16384 + i*1024);
    };
    auto MF = [&]() {
        __builtin_amdgcn_s_setprio(1);
        #pragma unroll
        for (int i = 0; i < 4; i++)
            #pragma unroll
            for (int ni = 0; ni < 4; ni++)
                acc[i][ni] = __builtin_amdgcn_mfma_f32_16x16x32_bf16(
                    a[i], b[ni], acc[i][ni], 0, 0, 0);
        __builtin_amdgcn_s_setprio(0);
    };

    // prologue: stage tiles 0,1; land tile 0 (keep tile 1's 4 in flight)
    STAGE(0, 0); STAGE(1, 1);
    asm volatile("s_waitcnt vmcnt(4)" ::: "memory");
    block_barrier();

    #pragma unroll
    for (int kt = 0; kt < NT; ++kt) {
        const int bR = kt % 3;
        RD(bR);                              // reads span the barrier (lgkm)
        if (kt + 2 < NT) {
            STAGE(kt + 2, (kt + 2) % 3);
            asm volatile("s_waitcnt vmcnt(4)" ::: "memory");  // land kt+1
        } else if (kt + 1 < NT) {
            asm volatile("s_waitcnt vmcnt(0)" ::: "memory");  // land last tile
        }
        block_barrier();
        MF();
        if (kt + 1 < NT) block_barrier();
    }

    // epilogue (C/D mapping: col = lane&15, row = (lane>>4)*4 + reg)
    if (EPI == EPI_QBF) {
        #pragma unroll
        for (int mi = 0; mi < 4; mi++) {
            #pragma unroll
            for (int r = 0; r < 4; r++) {
                const int rr = row0 + wr*64 + mi*16 + ((l >> 4) << 2) + r;
                float ssq = 0.0f;
                #pragma unroll
                for (int ni = 0; ni < 4; ni++) {
                    const int c = col0 + wc*64 + ni*16 + (l & 15);
                    const float val = acc[mi][ni][r] + bias[c];
                    ((__hip_bfloat16*)Cout)[(size_t)rr * N + c] = __float2bfloat16(val);
                    ssq += val * val;
                }
                #pragma unroll
                for (int o = 1; o < 16; o <<= 1) ssq += __shfl_xor(ssq, o);
                if ((l & 15) == 0) atomicAdd((float*)xres + rr, ssq);
            }
        }
        return;
    }

    const float alpha = (EPI == EPI_WO) ? alpha_p[0] : 0.0f;
    #pragma unroll
    for (int mi = 0; mi < 4; mi++) {
        const int rbase = row0 + wr*64 + mi*16 + ((l >> 4) << 2);
        #pragma unroll
        for (int ni = 0; ni < 4; ni++) {
            const int c = col0 + wc*64 + ni*16 + (l & 15);
            const float bc = bias[c];
            #pragma unroll
            for (int r = 0; r < 4; r++) {
                const int rr = rbase + r;
                const size_t idx = (size_t)rr * N + c;
                float val = acc[mi][ni][r] + bc;
                if (EPI == EPI_GELU) {
                    const float u = 1.5957691216f * val
                                  + 0.0713548163f * val * val * val;
                    val = val / (1.0f + __expf(-u));
                    ((__hip_bfloat16*)Cout)[idx] = __float2bfloat16(val);
                } else if (EPI == EPI_WO) {
                    ((float*)Cout)[idx] = xres[idx] + alpha * gate[rr] * val;
                } else if (EPI == EPI_RES) {
                    ((float*)Cout)[idx] = bfbits2f(((const short*)yres)[idx]) + val;
                } else {
                    ((float*)Cout)[idx] = val;
                }
            }
        }
    }
}

// ---------------------------------------------------------------------------
// bf16 MFMA GEMM, 256x128 tile, BK=32, 256 threads, 4x1 wave grid: wave w
// owns rows w*64..+63 x ALL 128 cols (wave tile 64x128 -> 42.7 FLOP/LDS-byte,
// +33% over 64x64; r15 counters: LDS read pipe is the binder at MfmaUtil 30%).
// Ring-2 LDS 2x(A 16KB + B 8KB) = 48 KiB -> SAME 3 blocks/CU / 12 waves/CU as
// r11 (r10's occupancy-loss trap avoided). WAR by architecture: STAGE(t+2)
// into buf t%2 only after the post-MFMA barrier (all reads consumed); then
// vmcnt(6) + barrier lands t+1 for every wave's chunks. FFN1 only.
// ---------------------------------------------------------------------------
template<int NT, int EPI>
__global__ __launch_bounds__(256, 3)
void bgemm256_kernel(const __hip_bfloat16* __restrict__ Ah,
                     const __hip_bfloat16* __restrict__ Bth,
                     const float* __restrict__ bias,
                     void* __restrict__ Cout,
                     int M, int N)
{
    constexpr int K = NT * 32;
    __shared__ short lds[2 * 12288];  // 48 KiB: 2 bufs x (A 8192 + B 4096 shorts)

    const short* A  = (const short*)Ah;
    const short* Bt = (const short*)Bth;

    // XCD-aware bijective swizzle
    const int nwg = gridDim.x;
    const int cpx = nwg >> 3;
    const int bid0 = blockIdx.x;
    const int bid = (bid0 & 7) * cpx + (bid0 >> 3);
    const int cols = N >> 7;
    const int row0 = (bid / cols) << 8;      // M tile 256
    const int col0 = (bid % cols) << 7;      // N tile 128

    const int t = threadIdx.x;
    const int w = t >> 6, l = t & 63;

    // ---- staging source pointers (lane-fixed); T2 pre-swizzled source ----
    const int src_kelem = (((l & 3) ^ ((l >> 3) & 3)) << 3);
    const int srow = w*16 + (l >> 2);
    const short* pA_[4];
    const short* pB_[2];
    #pragma unroll
    for (int j = 0; j < 4; j++)
        pA_[j] = A + (size_t)(row0 + j*64 + srow) * K + src_kelem;
    #pragma unroll
    for (int j = 0; j < 2; j++)
        pB_[j] = Bt + (size_t)(col0 + j*64 + srow) * K + src_kelem;

    auto STAGE = [&](int kt, int bW) {
        const int ro = bW * 12288;           // shorts
        #pragma unroll
        for (int j = 0; j < 4; j++)
            gload16(pA_[j] + kt * 32, lds + ro + (j*64 + w*16) * 32);
        #pragma unroll
        for (int j = 0; j < 2; j++)
            gload16(pB_[j] + kt * 32, lds + ro + 8192 + (j*64 + w*16) * 32);
    };

    // ---- fragment read bases ----
    const int axk = (((l >> 4) << 4) ^ (((l >> 1) & 3) << 4));
    const char* const bA = (const char*)lds + (w*64 + (l & 15))*64 + axk;
    const char* const bB = (const char*)(lds + 8192) + ((l & 15))*64 + axk;

    bf16x8 a[4], b[8];
    f32x4 acc[4][8] = {};

    auto RD = [&](int bR) {
        #pragma unroll
        for (int i = 0; i < 4; i++)
            a[i] = *(const bf16x8*)(bA + bR*24576 + i*1024);
        #pragma unroll
        for (int i = 0; i < 8; i++)
            b[i] = *(const bf16x8*)(bB + bR*24576 + i*1024);
    };
    auto MF = [&]() {
        #pragma unroll
        for (int i = 0; i < 4; i++)
            #pragma unroll
            for (int ni = 0; ni < 8; ni++)
                acc[i][ni] = __builtin_amdgcn_mfma_f32_16x16x32_bf16(
                    a[i], b[ni], acc[i][ni], 0, 0, 0);
    };

    // prologue: stage tiles 0,1 (6 loads each); land tile 0
    STAGE(0, 0); STAGE(1, 1);
    asm volatile("s_waitcnt vmcnt(6)" ::: "memory");
    block_barrier();

    #pragma unroll
    for (int kt = 0; kt < NT; ++kt) {
        RD(kt & 1);
        MF();                                // consumes buf kt&1 (lgkm waits)
        if (kt + 1 < NT) {
            block_barrier();                 // all waves done reading buf kt&1
            if (kt + 2 < NT) {
                STAGE(kt + 2, kt & 1);       // safe overwrite
                asm volatile("s_waitcnt vmcnt(6)" ::: "memory");  // land kt+1
            } else {
                asm volatile("s_waitcnt vmcnt(0)" ::: "memory");
            }
            block_barrier();                 // all waves landed kt+1
        }
    }

    // epilogue (C/D mapping: col = lane&15, row = (lane>>4)*4 + reg)
    #pragma unroll
    for (int mi = 0; mi < 4; mi++) {
        const int rbase = row0 + w*64 + mi*16 + ((l >> 4) << 2);
        #pragma unroll
        for (int ni = 0; ni < 8; ni++) {
            const int c = col0 + ni*16 + (l & 15);
            const float bc = bias[c];
            #pragma unroll
            for (int r = 0; r < 4; r++) {
                const int rr = rbase + r;
                const size_t idx = (size_t)rr * N + c;
                float val = acc[mi][ni][r] + bc;
                if (EPI == EPI_GELU) {
                    const float u = 1.5957691216f * val
                                  + 0.0713548163f * val * val * val;
                    val = val / (1.0f + __expf(-u));
                    ((__hip_bfloat16*)Cout)[idx] = __float2bfloat16(val);
                } else {
                    ((float*)Cout)[idx] = val;
                }
            }
        }
    }
}

// ---------------------------------------------------------------------------
// MFMA attention: block = (b, h, 256-row tile), 4 waves x 64 rows.
// Swapped QK^T (r14-verified). q-norm from folded qsum (rsqrt at staging).
// ---------------------------------------------------------------------------
__global__ __launch_bounds__(256)
void attn_kernel(const __hip_bfloat16* __restrict__ qf,
                 const __hip_bfloat16* __restrict__ kbf,
                 const float* __restrict__ vf,
                 const float* __restrict__ qsum,
                 const float* __restrict__ msk,
                 const float* __restrict__ logit_scale,
                 __hip_bfloat16* __restrict__ out)
{
    __shared__ short kb[80 * 72];        // 80 keys x 64 bf16, stride 72 (144B)
    __shared__ float v_lds[Tt][68];
    __shared__ float qinv_s[256];
    __shared__ float bias_s[80];

    const int gid = blockIdx.x;
    const int b = gid >> 7;
    const int h = (gid >> 4) & 7;
    const int ntile = gid & 15;
    const int t = threadIdx.x;
    const int row0 = b * Nv + ntile * 256;

    // stage K (pre-normalized bf16): 77 rows x 8 chunks of 16B = 616 chunks
    #pragma unroll
    for (int it = 0; it < 3; ++it) {
        const int ch = t + it * 256;
        if (ch < 616) {
            const int row = ch >> 3, part = ch & 7;
            *(bf16x8*)&kb[row * 72 + part * 8] =
                *(const bf16x8*)(kbf + (size_t)(b * Tt + row) * Cvd + h * Dh + part * 8);
        }
    }
    if (t < 27) {
        const bf16x8 z = {0,0,0,0,0,0,0,0};
        *(bf16x8*)&kb[77 * 72 + t * 8] = z;
    }
    for (int idx = t; idx < Tt * Dh; idx += 256) {
        const int tt = idx >> 6, dd = idx & 63;
        v_lds[tt][dd] = vf[(size_t)(b * Tt + tt) * Cvd + h * Dh + dd];
    }
    qinv_s[t] = 1.0f / fmaxf(sqrtf(qsum[row0 + t]), 1e-6f);
    if (t < 80) bias_s[t] = (t < 77 && msk[b * Tt + t] == 0.0f) ? 0.0f : -1e30f;
    __syncthreads();

    float ls = logit_scale[0];
    ls = fminf(fmaxf(ls, -2.0f), 2.0f);
    const float scale = __expf(ls) * 0.125f;

    const int w = t >> 6, l = t & 63;
    const int c = l & 15, g = l >> 4;

    // prefetch Q B-frags for all 4 row-tiles x 2 k-halves
    bf16x8 qfrag[8];
    #pragma unroll
    for (int rt = 0; rt < 4; ++rt)
        #pragma unroll
        for (int kk = 0; kk < 2; ++kk)
            qfrag[rt*2 + kk] = *(const bf16x8*)(qf +
                (size_t)(row0 + w*64 + rt*16 + c) * Cvd + h * Dh + kk*32 + g*8);

    #pragma unroll
    for (int rt = 0; rt < 4; ++rt) {
        const int lrow = w*64 + rt*16 + c;
        const float qsc = qinv_s[lrow] * scale;

        float v0=-INFINITY,v1=-INFINITY,v2=-INFINITY,v3=-INFINITY,v4=-INFINITY;
        int   i0=0,i1=0,i2=0,i3=0,i4=0;
        auto INS = [&](float s, int idx) {
            const bool c0=s>v0, c1=s>v1, c2=s>v2, c3=s>v3, c4=s>v4;
            const float nv0=c0?s:v0;              const int ni0=c0?idx:i0;
            const float nv1=c1?(c0?v0:s):v1;      const int ni1=c1?(c0?i0:idx):i1;
            const float nv2=c2?(c1?v1:s):v2;      const int ni2=c2?(c1?i1:idx):i2;
            const float nv3=c3?(c2?v2:s):v3;      const int ni3=c3?(c2?i2:idx):i3;
            const float nv4=c4?(c3?v3:s):v4;      const int ni4=c4?(c3?i3:idx):i4;
            v0=nv0;v1=nv1;v2=nv2;v3=nv3;v4=nv4;
            i0=ni0;i1=ni1;i2=ni2;i3=ni3;i4=ni4;
        };

        #pragma unroll
        for (int kt = 0; kt < 5; ++kt) {
            f32x4 acc = {0.f, 0.f, 0.f, 0.f};
            const bf16x8 ka0 = *(const bf16x8*)&kb[(kt*16 + c) * 72 + g*8];
            const bf16x8 ka1 = *(const bf16x8*)&kb[(kt*16 + c) * 72 + 32 + g*8];
            acc = __builtin_amdgcn_mfma_f32_16x16x32_bf16(ka0, qfrag[rt*2+0], acc, 0, 0, 0);
            acc = __builtin_amdgcn_mfma_f32_16x16x32_bf16(ka1, qfrag[rt*2+1], acc, 0, 0, 0);
            #pragma unroll
            for (int r = 0; r < 4; ++r) {
                const int key = kt*16 + g*4 + r;
                INS(acc[r] * qsc + bias_s[key], key);
            }
        }

        // merge across the 4 lanes sharing q-row c (xor 16, then 32)
        #pragma unroll
        for (int st = 16; st <= 32; st <<= 1) {
            const float m0=__shfl_xor(v0,st), m1=__shfl_xor(v1,st),
                        m2=__shfl_xor(v2,st), m3=__shfl_xor(v3,st),
                        m4=__shfl_xor(v4,st);
            const int   j0=__shfl_xor(i0,st), j1=__shfl_xor(i1,st),
                        j2=__shfl_xor(i2,st), j3=__shfl_xor(i3,st),
                        j4=__shfl_xor(i4,st);
            INS(m0,j0); INS(m1,j1); INS(m2,j2); INS(m3,j3); INS(m4,j4);
        }

        const float e1=__expf(v1-v0), e2=__expf(v2-v0),
                    e3=__expf(v3-v0), e4=__expf(v4-v0);
        const float inv = 1.0f / (1.0f + e1 + e2 + e3 + e4);
        const float w0=inv, w1=e1*inv, w2=e2*inv, w3=e3*inv, w4=e4*inv;

        // PV: lane g covers dims g*16 .. g*16+16
        float o[16];
        #pragma unroll
        for (int d4 = 0; d4 < 4; ++d4) {
            const int dd = g*16 + d4*4;
            const float4 p0 = *(const float4*)&v_lds[i0][dd];
            const float4 p1 = *(const float4*)&v_lds[i1][dd];
            const float4 p2 = *(const float4*)&v_lds[i2][dd];
            const float4 p3 = *(const float4*)&v_lds[i3][dd];
            const float4 p4 = *(const float4*)&v_lds[i4][dd];
            o[d4*4+0] = w0*p0.x + w1*p1.x + w2*p2.x + w3*p3.x + w4*p4.x;
            o[d4*4+1] = w0*p0.y + w1*p1.y + w2*p2.y + w3*p3.y + w4*p4.y;
            o[d4*4+2] = w0*p0.z + w1*p1.z + w2*p2.z + w3*p3.z + w4*p4.z;
            o[d4*4+3] = w0*p0.w + w1*p1.w + w2*p2.w + w3*p3.w + w4*p4.w;
        }
        __hip_bfloat16* op = out + (size_t)(row0 + lrow) * Cvd + h * Dh + g*16;
        bf16x8 s0, s1;
        #pragma unroll
        for (int j = 0; j < 8; ++j) { s0[j] = f2bfbits(o[j]); s1[j] = f2bfbits(o[8+j]); }
        *(bf16x8*)op       = s0;
        *(bf16x8*)(op + 8) = s1;
    }
}

// ---------------------------------------------------------------------------
extern "C" void kernel_launch(void* const* d_in, const int* in_sizes, int n_in,
                              void* d_out, int out_size, void* d_ws, size_t ws_size,
                              hipStream_t stream)
{
    const float* visual = (const float*)d_in[0];
    const float* text   = (const float*)d_in[1];
    const float* n1w = (const float*)d_in[2];
    const float* n1b = (const float*)d_in[3];
    const float* Wq  = (const float*)d_in[4];
    const float* bq  = (const float*)d_in[5];
    const float* Wk  = (const float*)d_in[6];
    const float* bk  = (const float*)d_in[7];
    const float* Wv  = (const float*)d_in[8];
    const float* bv  = (const float*)d_in[9];
    const float* Wo  = (const float*)d_in[10];
    const float* bo  = (const float*)d_in[11];
    const float* gw  = (const float*)d_in[12];
    const float* gb  = (const float*)d_in[13];
    const float* n2w = (const float*)d_in[14];
    const float* n2b = (const float*)d_in[15];
    const float* w1  = (const float*)d_in[16];
    const float* b1  = (const float*)d_in[17];
    const float* w2  = (const float*)d_in[18];
    const float* b2  = (const float*)d_in[19];
    const float* lsc = (const float*)d_in[20];
    const float* alp = (const float*)d_in[21];

    float* out = (float*)d_out;
    char*  w8  = (char*)d_ws;

    // workspace (byte offsets, aliased by lifetime):
    __hip_bfloat16* qbf    = (__hip_bfloat16*)(w8 + 0);          // q_full bf16
    float*          ypre   = (float*)(w8 + 67108864);
    __hip_bfloat16* hidden = (__hip_bfloat16*)(w8 + 0);          // after q dead
    __hip_bfloat16* xbf    = (__hip_bfloat16*)(w8 + 134217728);  // x/attnout/y
    float*          kf     = (float*)(w8 + 167772160);
    float*          vf     = (float*)(w8 + 169033728);
    float*          qsum   = (float*)(w8 + 170295296);           // 128 KiB
    float*          mskp   = (float*)(w8 + 170428832);
    float*          gate   = (float*)(w8 + 170431296);
    __hip_bfloat16* WqT    = (__hip_bfloat16*)(w8 + 170562368);
    __hip_bfloat16* WoT    = (__hip_bfloat16*)(w8 + 171086656);
    __hip_bfloat16* w1T    = (__hip_bfloat16*)(w8 + 171610944);
    __hip_bfloat16* w2T    = (__hip_bfloat16*)(w8 + 173708096);
    __hip_bfloat16* kbfg   = (__hip_bfloat16*)(w8 + 175805248);  // k-hat bf16

    // 0. all weight transposes in one launch; zero qsum for the atomic fold
    wtrans4_kernel<<<dim3(2560), dim3(256), 0, stream>>>(
        Wq, Wo, w1, w2, WqT, WoT, w1T, w2T);
    hipMemsetAsync(qsum, 0, MROWS * sizeof(float), stream);

    // 1. LN1: x -> d_out (f32 residual) + xbf (bf16); gate logits
    ln_kernel<true, true><<<dim3(MROWS), dim3(128), 0, stream>>>(
        visual, n1w, n1b, out, xbf, gw, gb, gate);

    // 2. q_full = x @ Wq + bq -> bf16 + folded row sum-of-squares (qsum)
    bgemm_kernel<16, EPI_QBF><<<dim3(1024), dim3(256), 0, stream>>>(
        xbf, WqT, bq, qbf, MROWS, 512, qsum, nullptr, nullptr, nullptr);

    // 3. k_full / v_full in one launch (fp32, tiny M=616)
    gemm32kv_kernel<<<dim3(8, 10, 2), dim3(256), 0, stream>>>(
        text, Wk, bk, kf, Wv, bv, vf, KTROWS, 512);

    // 4. k norm + pad mask + pre-normalized bf16 k-hat
    knorm_mask_kernel<<<dim3(KTROWS), dim3(64), 0, stream>>>(kf, text, mskp, kbfg);

    // 5. MFMA attention -> attnout bf16 (reuses xbf buffer; x_bf16 dead)
    attn_kernel<<<dim3(1024), dim3(256), 0, stream>>>(
        qbf, kbfg, vf, qsum, mskp, lsc, xbf);

    // 6. y_pre = x + alpha*gate*(attnout @ Wo + bo)
    bgemm_kernel<16, EPI_WO><<<dim3(1024), dim3(256), 0, stream>>>(
        xbf, WoT, bo, ypre, MROWS, 512, out, gate, alp, nullptr);

    // 7. y = LN2(y_pre) -> bf16 only (residual for FFN2 read as bf16)
    ln_kernel<false, false><<<dim3(MROWS), dim3(128), 0, stream>>>(
        ypre, n2w, n2b, nullptr, xbf, nullptr, nullptr, nullptr);

    // 8. hidden = gelu(y @ w1 + b1) -> bf16; 256x128 tile: grid 128*16 = 2048
    bgemm256_kernel<16, EPI_GELU><<<dim3(2048), dim3(256), 0, stream>>>(
        xbf, w1T, b1, hidden, MROWS, 2048);

    // 9. out = bf16(y) + hidden @ w2 + b2; y-residual from xbf (bf16)
    bgemm_kernel<64, EPI_RES><<<dim3(1024), dim3(256), 0, stream>>>(
        hidden, w2T, b2, out, MROWS, 512, nullptr, nullptr, nullptr, xbf);
}

// Round 17
// 379.426 us; speedup vs baseline: 1.4814x; 1.4814x over previous
//
#include <hip/hip_runtime.h>
#include <hip/hip_bf16.h>
#include <math.h>

// Problem constants (from reference)
constexpr int Bv = 8;
constexpr int Nv = 4096;      // H*W = 64*64
constexpr int Cvd = 512;
constexpr int Tt = 77;
constexpr int Dh = 64;
constexpr int MROWS = Bv * Nv;   // 32768
constexpr int KTROWS = Bv * Tt;  // 616

typedef __attribute__((ext_vector_type(8))) short bf16x8;
typedef __attribute__((ext_vector_type(4))) float f32x4;

__device__ __forceinline__ float bfbits2f(short s) {
    unsigned int u = ((unsigned int)(unsigned short)s) << 16;
    return __uint_as_float(u);
}
__device__ __forceinline__ short f2bfbits(float f) {
    __hip_bfloat16 h = __float2bfloat16(f);
    return *reinterpret_cast<short*>(&h);
}

// ---------------------------------------------------------------------------
// async global->LDS, 16B per lane. LDS dest wave-uniform base; HW adds lane*16.
// ---------------------------------------------------------------------------
__device__ __forceinline__ void gload16(const void* g, void* l) {
    __builtin_amdgcn_global_load_lds(
        (const __attribute__((address_space(1))) void*)g,
        (__attribute__((address_space(3))) void*)l, 16, 0, 0);
}

// raw barrier with compiler memory fences (NO vmcnt drain)
__device__ __forceinline__ void block_barrier() {
    asm volatile("" ::: "memory");
    __builtin_amdgcn_s_barrier();
    asm volatile("" ::: "memory");
}

// ---------------------------------------------------------------------------
// All 4 weight transposes in ONE launch: fp32[K,N] -> bf16[N,K].
// ---------------------------------------------------------------------------
__global__ __launch_bounds__(256)
void wtrans4_kernel(const float* __restrict__ Wq, const float* __restrict__ Wo,
                    const float* __restrict__ w1, const float* __restrict__ w2,
                    __hip_bfloat16* __restrict__ WqT, __hip_bfloat16* __restrict__ WoT,
                    __hip_bfloat16* __restrict__ w1T, __hip_bfloat16* __restrict__ w2T)
{
    __shared__ float tile[32][33];
    const int bid = blockIdx.x;
    const float* in;
    __hip_bfloat16* out;
    int K, N, tid;
    if (bid < 256)       { in = Wq; out = WqT; K = 512;  N = 512;  tid = bid; }
    else if (bid < 512)  { in = Wo; out = WoT; K = 512;  N = 512;  tid = bid - 256; }
    else if (bid < 1536) { in = w1; out = w1T; K = 512;  N = 2048; tid = bid - 512; }
    else                 { in = w2; out = w2T; K = 2048; N = 512;  tid = bid - 1536; }
    const int nx = N >> 5;
    const int n0 = (tid % nx) * 32, k0 = (tid / nx) * 32;
    const int tx = threadIdx.x & 31, ty = threadIdx.x >> 5;
    #pragma unroll
    for (int i = ty; i < 32; i += 8)
        tile[i][tx] = in[(size_t)(k0 + i) * N + n0 + tx];
    __syncthreads();
    #pragma unroll
    for (int i = ty; i < 32; i += 8)
        out[(size_t)(n0 + i) * K + k0 + tx] = __float2bfloat16(tile[tx][i]);
}

// ---------------------------------------------------------------------------
// LayerNorm row of 512, 128 threads; f32 or bf16 input; writes bf16
// (+ optional f32 copy, gate logit)
// ---------------------------------------------------------------------------
template<bool GATE, bool WF32, bool BFIN>
__global__ __launch_bounds__(128)
void ln_kernel(const void* __restrict__ in, const float* __restrict__ w,
               const float* __restrict__ b, float* __restrict__ out,
               __hip_bfloat16* __restrict__ out_bf,
               const float* __restrict__ gate_w, const float* __restrict__ gate_b,
               float* __restrict__ gate_out)
{
    __shared__ float red[4];
    __shared__ float redg[2];
    const int row = blockIdx.x;
    const int t = threadIdx.x;
    const int wv = t >> 6;
    float4 v;
    if (BFIN) {
        const short4 sv = ((const short4*)in)[(size_t)row * 128 + t];
        v.x = bfbits2f(sv.x); v.y = bfbits2f(sv.y);
        v.z = bfbits2f(sv.z); v.w = bfbits2f(sv.w);
    } else {
        v = ((const float4*)in)[(size_t)row * 128 + t];
    }

    float s  = v.x + v.y + v.z + v.w;
    float ss = v.x*v.x + v.y*v.y + v.z*v.z + v.w*v.w;
    #pragma unroll
    for (int o = 1; o < 64; o <<= 1) {
        s  += __shfl_xor(s,  o);
        ss += __shfl_xor(ss, o);
    }
    if ((t & 63) == 0) { red[wv*2] = s; red[wv*2+1] = ss; }
    __syncthreads();
    s  = red[0] + red[2];
    ss = red[1] + red[3];
    const float m   = s * (1.0f / 512.0f);
    const float var = ss * (1.0f / 512.0f) - m * m;
    const float rs  = 1.0f / sqrtf(var + 1e-5f);

    const float4 w4 = ((const float4*)w)[t];
    const float4 b4 = ((const float4*)b)[t];
    float4 o4;
    o4.x = (v.x - m) * rs * w4.x + b4.x;
    o4.y = (v.y - m) * rs * w4.y + b4.y;
    o4.z = (v.z - m) * rs * w4.z + b4.z;
    o4.w = (v.w - m) * rs * w4.w + b4.w;
    if (WF32) ((float4*)(out + (size_t)row * Cvd))[t] = o4;

    __hip_bfloat162 h0, h1;
    h0.x = __float2bfloat16(o4.x); h0.y = __float2bfloat16(o4.y);
    h1.x = __float2bfloat16(o4.z); h1.y = __float2bfloat16(o4.w);
    __hip_bfloat16* obp = out_bf + (size_t)row * Cvd + 4*t;
    *(__hip_bfloat162*)(obp)     = h0;
    *(__hip_bfloat162*)(obp + 2) = h1;

    if (GATE) {
        const float4 g4 = ((const float4*)gate_w)[t];
        float g = o4.x*g4.x + o4.y*g4.y + o4.z*g4.z + o4.w*g4.w;
        #pragma unroll
        for (int o = 1; o < 64; o <<= 1) g += __shfl_xor(g, o);
        if ((t & 63) == 0) redg[wv] = g;
        __syncthreads();
        if (t == 0) {
            const float gt = redg[0] + redg[1] + gate_b[0];
            gate_out[row] = 1.0f / (1.0f + expf(-gt));
        }
    }
}

// ---------------------------------------------------------------------------
// k norm + pad mask + PRE-NORMALIZED bf16 k output (kbf = bf16(k * kinv))
// ---------------------------------------------------------------------------
__global__ __launch_bounds__(64)
void knorm_mask_kernel(const float* __restrict__ kf, const float* __restrict__ text,
                       float* __restrict__ msk, __hip_bfloat16* __restrict__ kbf)
{
    const int row = blockIdx.x;
    const int l = threadIdx.x;
    const float4* rp = (const float4*)(kf + (size_t)row * Cvd);
    const float4* tp = (const float4*)(text + (size_t)row * Cvd);
    const float4 a = rp[l], c = rp[l + 64];
    const float4 ta = tp[l], tc = tp[l + 64];
    float ss = a.x*a.x + a.y*a.y + a.z*a.z + a.w*a.w
             + c.x*c.x + c.y*c.y + c.z*c.z + c.w*c.w;
    float sa = fabsf(ta.x)+fabsf(ta.y)+fabsf(ta.z)+fabsf(ta.w)
             + fabsf(tc.x)+fabsf(tc.y)+fabsf(tc.z)+fabsf(tc.w);
    #pragma unroll
    for (int o = 1; o < 64; o <<= 1) {
        ss += __shfl_xor(ss, o);
        sa += __shfl_xor(sa, o);
    }
    const float ki = 1.0f / fmaxf(sqrtf(ss), 1e-6f);
    if (l == 0) msk[row] = (sa <= 1e-6f) ? 1.0f : 0.0f;

    __hip_bfloat16* kp = kbf + (size_t)row * Cvd;
    __hip_bfloat162 p;
    p.x = __float2bfloat16(a.x * ki); p.y = __float2bfloat16(a.y * ki);
    *(__hip_bfloat162*)(kp + l*4)     = p;
    p.x = __float2bfloat16(a.z * ki); p.y = __float2bfloat16(a.w * ki);
    *(__hip_bfloat162*)(kp + l*4 + 2) = p;
    p.x = __float2bfloat16(c.x * ki); p.y = __float2bfloat16(c.y * ki);
    *(__hip_bfloat162*)(kp + (l+64)*4)     = p;
    p.x = __float2bfloat16(c.z * ki); p.y = __float2bfloat16(c.w * ki);
    *(__hip_bfloat162*)(kp + (l+64)*4 + 2) = p;
}

// ---------------------------------------------------------------------------
// fp32 tiled GEMM for BOTH k and v projections in one launch (blockIdx.z)
// ---------------------------------------------------------------------------
__global__ __launch_bounds__(256)
void gemm32kv_kernel(const float* __restrict__ A,
                     const float* __restrict__ Wk, const float* __restrict__ bk,
                     float* __restrict__ Ck,
                     const float* __restrict__ Wv, const float* __restrict__ bv,
                     float* __restrict__ Cv2,
                     int M, int K)
{
    __shared__ float As[16][64 + 4];
    __shared__ float Bs[16][64 + 4];

    const float* W    = blockIdx.z ? Wv  : Wk;
    const float* bias = blockIdx.z ? bv  : bk;
    float*       C    = blockIdx.z ? Cv2 : Ck;

    const int t = threadIdx.x;
    const int tx = t & 15, ty = t >> 4;
    const int row0 = blockIdx.y * 64;
    const int col0 = blockIdx.x * 64;

    const int arow = t >> 2;
    const int ak   = (t & 3) << 2;
    const int brow = t >> 4;
    const int bcol = (t & 15) << 2;

    float acc[4][4] = {};

    for (int kt = 0; kt < K; kt += 16) {
        float4 a4 = make_float4(0.f, 0.f, 0.f, 0.f);
        const int gr = row0 + arow;
        if (gr < M) a4 = *(const float4*)(A + (size_t)gr * 512 + kt + ak);
        As[ak + 0][arow] = a4.x;
        As[ak + 1][arow] = a4.y;
        As[ak + 2][arow] = a4.z;
        As[ak + 3][arow] = a4.w;
        const float4 b4 = *(const float4*)(W + (size_t)(kt + brow) * 512 + col0 + bcol);
        *(float4*)&Bs[brow][bcol] = b4;
        __syncthreads();
        #pragma unroll
        for (int k = 0; k < 16; k++) {
            const float4 av = *(const float4*)&As[k][ty << 2];
            const float4 bv4 = *(const float4*)&Bs[k][tx << 2];
            acc[0][0] += av.x * bv4.x; acc[0][1] += av.x * bv4.y;
            acc[0][2] += av.x * bv4.z; acc[0][3] += av.x * bv4.w;
            acc[1][0] += av.y * bv4.x; acc[1][1] += av.y * bv4.y;
            acc[1][2] += av.y * bv4.z; acc[1][3] += av.y * bv4.w;
            acc[2][0] += av.z * bv4.x; acc[2][1] += av.z * bv4.y;
            acc[2][2] += av.z * bv4.z; acc[2][3] += av.z * bv4.w;
            acc[3][0] += av.w * bv4.x; acc[3][1] += av.w * bv4.y;
            acc[3][2] += av.w * bv4.z; acc[3][3] += av.w * bv4.w;
        }
        __syncthreads();
    }

    #pragma unroll
    for (int i = 0; i < 4; i++) {
        const int r = row0 + (ty << 2) + i;
        if (r >= M) continue;
        #pragma unroll
        for (int j = 0; j < 4; j++) {
            const int c = col0 + (tx << 2) + j;
            C[(size_t)r * 512 + c] = acc[i][j] + bias[c];
        }
    }
}

// ---------------------------------------------------------------------------
// bf16 MFMA GEMM, 128x128 tile, BK=32, 256 threads (4 waves 2x2).
// Round-11 verified config (structurally converged; geometry alternatives
// falsified r10/r12/r16): ring-3 LDS (48 KiB, 3 blocks/CU), staged 2 ahead,
// counted vmcnt(4), full K-unroll, T2 swizzle (0 conflicts), ~667 TF.
// EPI_QBF: + per-row sum(val^2) -> atomicAdd(qsum). EPI_WO: writes bf16
// (r17: halves ypre traffic). EPI_RES: bf16 y residual.
// ---------------------------------------------------------------------------
enum { EPI_NONE = 0, EPI_WO = 1, EPI_GELU = 2, EPI_RES = 3, EPI_QBF = 4 };

template<int NT, int EPI>
__global__ __launch_bounds__(256, 3)
void bgemm_kernel(const __hip_bfloat16* __restrict__ Ah,
                  const __hip_bfloat16* __restrict__ Bth,
                  const float* __restrict__ bias,
                  void* __restrict__ Cout,
                  int M, int N,
                  const float* __restrict__ xres,
                  const float* __restrict__ gate,
                  const float* __restrict__ alpha_p,
                  const void* __restrict__ yres)
{
    constexpr int K = NT * 32;
    __shared__ short lds[3 * 8192];   // 48 KiB: 3 bufs x (A 4096 + B 4096 shorts)

    const short* A  = (const short*)Ah;
    const short* Bt = (const short*)Bth;

    // XCD-aware bijective swizzle (nwg % 8 == 0 for all our shapes)
    const int nwg = gridDim.x;
    const int cpx = nwg >> 3;
    const int bid0 = blockIdx.x;
    const int bid = (bid0 & 7) * cpx + (bid0 >> 3);
    const int cols = N >> 7;
    const int row0 = (bid / cols) << 7;
    const int col0 = (bid % cols) << 7;

    const int t = threadIdx.x;
    const int w = t >> 6, l = t & 63;
    const int wr = w >> 1, wc = w & 1;      // 2 x 2 wave grid

    // ---- staging source pointers (lane-fixed); T2 pre-swizzled source ----
    const int src_kelem = (((l & 3) ^ ((l >> 3) & 3)) << 3);
    const short* pA0;
    const short* pA1;
    const short* pB0;
    const short* pB1;
    {
        const int r0 = (2*w)*16 + (l >> 2);
        const int r1 = (2*w + 1)*16 + (l >> 2);
        pA0 = A  + (size_t)(row0 + r0) * K + src_kelem;
        pA1 = A  + (size_t)(row0 + r1) * K + src_kelem;
        pB0 = Bt + (size_t)(col0 + r0) * K + src_kelem;
        pB1 = Bt + (size_t)(col0 + r1) * K + src_kelem;
    }
    short* const dA = lds + (2*w) * 512;   // wave-uniform LDS dests (+ring off)
    short* const dB = lds + 4096 + (2*w) * 512;

    // kt, bW become compile-time constants after full unroll -> imm offsets
    auto STAGE = [&](int kt, int bW) {
        gload16(pA0 + kt * 32, dA + bW * 8192);
        gload16(pA1 + kt * 32, dA + bW * 8192 + 512);
        gload16(pB0 + kt * 32, dB + bW * 8192);
        gload16(pB1 + kt * 32, dB + bW * 8192 + 512);
    };

    // ---- fragment read bases (lane-fixed); per-read offsets all constant ----
    const int axk = (((l >> 4) << 4) ^ (((l >> 1) & 3) << 4));
    const char* const bA = (const char*)lds + (wr*64 + (l & 15))*64 + axk;
    const char* const bB = (const char*)lds + 8192 + (wc*64 + (l & 15))*64 + axk;

    bf16x8 a[4], b[4];
    f32x4 acc[4][4] = {};

    auto RD = [&](int bR) {
        #pragma unroll
        for (int i = 0; i < 4; i++)
            a[i] = *(const bf16x8*)(bA + bR*16384 + i*1024);
        #pragma unroll
        for (int i = 0; i < 4; i++)
            b[i] = *(const bf16x8*)(bB + bR*16384 + i*1024);
    };
    auto MF = [&]() {
        __builtin_amdgcn_s_setprio(1);
        #pragma unroll
        for (int i = 0; i < 4; i++)
            #pragma unroll
            for (int ni = 0; ni < 4; ni++)
                acc[i][ni] = __builtin_amdgcn_mfma_f32_16x16x32_bf16(
                    a[i], b[ni], acc[i][ni], 0, 0, 0);
        __builtin_amdgcn_s_setprio(0);
    };

    // prologue: stage tiles 0,1; land tile 0 (keep tile 1's 4 in flight)
    STAGE(0, 0); STAGE(1, 1);
    asm volatile("s_waitcnt vmcnt(4)" ::: "memory");
    block_barrier();

    #pragma unroll
    for (int kt = 0; kt < NT; ++kt) {
        const int bR = kt % 3;
        RD(bR);                              // reads span the barrier (lgkm)
        if (kt + 2 < NT) {
            STAGE(kt + 2, (kt + 2) % 3);
            asm volatile("s_waitcnt vmcnt(4)" ::: "memory");  // land kt+1
        } else if (kt + 1 < NT) {
            asm volatile("s_waitcnt vmcnt(0)" ::: "memory");  // land last tile
        }
        block_barrier();
        MF();
        if (kt + 1 < NT) block_barrier();
    }

    // epilogue (C/D mapping: col = lane&15, row = (lane>>4)*4 + reg)
    if (EPI == EPI_QBF) {
        #pragma unroll
        for (int mi = 0; mi < 4; mi++) {
            #pragma unroll
            for (int r = 0; r < 4; r++) {
                const int rr = row0 + wr*64 + mi*16 + ((l >> 4) << 2) + r;
                float ssq = 0.0f;
                #pragma unroll
                for (int ni = 0; ni < 4; ni++) {
                    const int c = col0 + wc*64 + ni*16 + (l & 15);
                    const float val = acc[mi][ni][r] + bias[c];
                    ((__hip_bfloat16*)Cout)[(size_t)rr * N + c] = __float2bfloat16(val);
                    ssq += val * val;
                }
                #pragma unroll
                for (int o = 1; o < 16; o <<= 1) ssq += __shfl_xor(ssq, o);
                if ((l & 15) == 0) atomicAdd((float*)xres + rr, ssq);
            }
        }
        return;
    }

    const float alpha = (EPI == EPI_WO) ? alpha_p[0] : 0.0f;
    #pragma unroll
    for (int mi = 0; mi < 4; mi++) {
        const int rbase = row0 + wr*64 + mi*16 + ((l >> 4) << 2);
        #pragma unroll
        for (int ni = 0; ni < 4; ni++) {
            const int c = col0 + wc*64 + ni*16 + (l & 15);
            const float bc = bias[c];
            #pragma unroll
            for (int r = 0; r < 4; r++) {
                const int rr = rbase + r;
                const size_t idx = (size_t)rr * N + c;
                float val = acc[mi][ni][r] + bc;
                if (EPI == EPI_GELU) {
                    const float u = 1.5957691216f * val
                                  + 0.0713548163f * val * val * val;
                    val = val / (1.0f + __expf(-u));
                    ((__hip_bfloat16*)Cout)[idx] = __float2bfloat16(val);
                } else if (EPI == EPI_WO) {
                    // r17: y_pre written as bf16 (halves ypre traffic)
                    ((__hip_bfloat16*)Cout)[idx] =
                        __float2bfloat16(xres[idx] + alpha * gate[rr] * val);
                } else if (EPI == EPI_RES) {
                    ((float*)Cout)[idx] = bfbits2f(((const short*)yres)[idx]) + val;
                } else {
                    ((float*)Cout)[idx] = val;
                }
            }
        }
    }
}

// ---------------------------------------------------------------------------
// MFMA attention: block = (b, h, 256-row tile), 4 waves x 64 rows.
// Swapped QK^T (r14-verified). q-norm from folded qsum (rsqrt at staging).
// ---------------------------------------------------------------------------
__global__ __launch_bounds__(256)
void attn_kernel(const __hip_bfloat16* __restrict__ qf,
                 const __hip_bfloat16* __restrict__ kbf,
                 const float* __restrict__ vf,
                 const float* __restrict__ qsum,
                 const float* __restrict__ msk,
                 const float* __restrict__ logit_scale,
                 __hip_bfloat16* __restrict__ out)
{
    __shared__ short kb[80 * 72];        // 80 keys x 64 bf16, stride 72 (144B)
    __shared__ float v_lds[Tt][68];
    __shared__ float qinv_s[256];
    __shared__ float bias_s[80];

    const int gid = blockIdx.x;
    const int b = gid >> 7;
    const int h = (gid >> 4) & 7;
    const int ntile = gid & 15;
    const int t = threadIdx.x;
    const int row0 = b * Nv + ntile * 256;

    // stage K (pre-normalized bf16): 77 rows x 8 chunks of 16B = 616 chunks
    #pragma unroll
    for (int it = 0; it < 3; ++it) {
        const int ch = t + it * 256;
        if (ch < 616) {
            const int row = ch >> 3, part = ch & 7;
            *(bf16x8*)&kb[row * 72 + part * 8] =
                *(const bf16x8*)(kbf + (size_t)(b * Tt + row) * Cvd + h * Dh + part * 8);
        }
    }
    if (t < 27) {
        const bf16x8 z = {0,0,0,0,0,0,0,0};
        *(bf16x8*)&kb[77 * 72 + t * 8] = z;
    }
    for (int idx = t; idx < Tt * Dh; idx += 256) {
        const int tt = idx >> 6, dd = idx & 63;
        v_lds[tt][dd] = vf[(size_t)(b * Tt + tt) * Cvd + h * Dh + dd];
    }
    qinv_s[t] = 1.0f / fmaxf(sqrtf(qsum[row0 + t]), 1e-6f);
    if (t < 80) bias_s[t] = (t < 77 && msk[b * Tt + t] == 0.0f) ? 0.0f : -1e30f;
    __syncthreads();

    float ls = logit_scale[0];
    ls = fminf(fmaxf(ls, -2.0f), 2.0f);
    const float scale = __expf(ls) * 0.125f;

    const int w = t >> 6, l = t & 63;
    const int c = l & 15, g = l >> 4;

    // prefetch Q B-frags for all 4 row-tiles x 2 k-halves
    bf16x8 qfrag[8];
    #pragma unroll
    for (int rt = 0; rt < 4; ++rt)
        #pragma unroll
        for (int kk = 0; kk < 2; ++kk)
            qfrag[rt*2 + kk] = *(const bf16x8*)(qf +
                (size_t)(row0 + w*64 + rt*16 + c) * Cvd + h * Dh + kk*32 + g*8);

    #pragma unroll
    for (int rt = 0; rt < 4; ++rt) {
        const int lrow = w*64 + rt*16 + c;
        const float qsc = qinv_s[lrow] * scale;

        float v0=-INFINITY,v1=-INFINITY,v2=-INFINITY,v3=-INFINITY,v4=-INFINITY;
        int   i0=0,i1=0,i2=0,i3=0,i4=0;
        auto INS = [&](float s, int idx) {
            const bool c0=s>v0, c1=s>v1, c2=s>v2, c3=s>v3, c4=s>v4;
            const float nv0=c0?s:v0;              const int ni0=c0?idx:i0;
            const float nv1=c1?(c0?v0:s):v1;      const int ni1=c1?(c0?i0:idx):i1;
            const float nv2=c2?(c1?v1:s):v2;      const int ni2=c2?(c1?i1:idx):i2;
            const float nv3=c3?(c2?v2:s):v3;      const int ni3=c3?(c2?i2:idx):i3;
            const float nv4=c4?(c3?v3:s):v4;      const int ni4=c4?(c3?i3:idx):i4;
            v0=nv0;v1=nv1;v2=nv2;v3=nv3;v4=nv4;
            i0=ni0;i1=ni1;i2=ni2;i3=ni3;i4=ni4;
        };

        #pragma unroll
        for (int kt = 0; kt < 5; ++kt) {
            f32x4 acc = {0.f, 0.f, 0.f, 0.f};
            const bf16x8 ka0 = *(const bf16x8*)&kb[(kt*16 + c) * 72 + g*8];
            const bf16x8 ka1 = *(const bf16x8*)&kb[(kt*16 + c) * 72 + 32 + g*8];
            acc = __builtin_amdgcn_mfma_f32_16x16x32_bf16(ka0, qfrag[rt*2+0], acc, 0, 0, 0);
            acc = __builtin_amdgcn_mfma_f32_16x16x32_bf16(ka1, qfrag[rt*2+1], acc, 0, 0, 0);
            #pragma unroll
            for (int r = 0; r < 4; ++r) {
                const int key = kt*16 + g*4 + r;
                INS(acc[r] * qsc + bias_s[key], key);
            }
        }

        // merge across the 4 lanes sharing q-row c (xor 16, then 32)
        #pragma unroll
        for (int st = 16; st <= 32; st <<= 1) {
            const float m0=__shfl_xor(v0,st), m1=__shfl_xor(v1,st),
                        m2=__shfl_xor(v2,st), m3=__shfl_xor(v3,st),
                        m4=__shfl_xor(v4,st);
            const int   j0=__shfl_xor(i0,st), j1=__shfl_xor(i1,st),
                        j2=__shfl_xor(i2,st), j3=__shfl_xor(i3,st),
                        j4=__shfl_xor(i4,st);
            INS(m0,j0); INS(m1,j1); INS(m2,j2); INS(m3,j3); INS(m4,j4);
        }

        const float e1=__expf(v1-v0), e2=__expf(v2-v0),
                    e3=__expf(v3-v0), e4=__expf(v4-v0);
        const float inv = 1.0f / (1.0f + e1 + e2 + e3 + e4);
        const float w0=inv, w1=e1*inv, w2=e2*inv, w3=e3*inv, w4=e4*inv;

        // PV: lane g covers dims g*16 .. g*16+16
        float o[16];
        #pragma unroll
        for (int d4 = 0; d4 < 4; ++d4) {
            const int dd = g*16 + d4*4;
            const float4 p0 = *(const float4*)&v_lds[i0][dd];
            const float4 p1 = *(const float4*)&v_lds[i1][dd];
            const float4 p2 = *(const float4*)&v_lds[i2][dd];
            const float4 p3 = *(const float4*)&v_lds[i3][dd];
            const float4 p4 = *(const float4*)&v_lds[i4][dd];
            o[d4*4+0] = w0*p0.x + w1*p1.x + w2*p2.x + w3*p3.x + w4*p4.x;
            o[d4*4+1] = w0*p0.y + w1*p1.y + w2*p2.y + w3*p3.y + w4*p4.y;
            o[d4*4+2] = w0*p0.z + w1*p1.z + w2*p2.z + w3*p3.z + w4*p4.z;
            o[d4*4+3] = w0*p0.w + w1*p1.w + w2*p2.w + w3*p3.w + w4*p4.w;
        }
        __hip_bfloat16* op = out + (size_t)(row0 + lrow) * Cvd + h * Dh + g*16;
        bf16x8 s0, s1;
        #pragma unroll
        for (int j = 0; j < 8; ++j) { s0[j] = f2bfbits(o[j]); s1[j] = f2bfbits(o[8+j]); }
        *(bf16x8*)op       = s0;
        *(bf16x8*)(op + 8) = s1;
    }
}

// ---------------------------------------------------------------------------
extern "C" void kernel_launch(void* const* d_in, const int* in_sizes, int n_in,
                              void* d_out, int out_size, void* d_ws, size_t ws_size,
                              hipStream_t stream)
{
    const float* visual = (const float*)d_in[0];
    const float* text   = (const float*)d_in[1];
    const float* n1w = (const float*)d_in[2];
    const float* n1b = (const float*)d_in[3];
    const float* Wq  = (const float*)d_in[4];
    const float* bq  = (const float*)d_in[5];
    const float* Wk  = (const float*)d_in[6];
    const float* bk  = (const float*)d_in[7];
    const float* Wv  = (const float*)d_in[8];
    const float* bv  = (const float*)d_in[9];
    const float* Wo  = (const float*)d_in[10];
    const float* bo  = (const float*)d_in[11];
    const float* gw  = (const float*)d_in[12];
    const float* gb  = (const float*)d_in[13];
    const float* n2w = (const float*)d_in[14];
    const float* n2b = (const float*)d_in[15];
    const float* w1  = (const float*)d_in[16];
    const float* b1  = (const float*)d_in[17];
    const float* w2  = (const float*)d_in[18];
    const float* b2  = (const float*)d_in[19];
    const float* lsc = (const float*)d_in[20];
    const float* alp = (const float*)d_in[21];

    float* out = (float*)d_out;
    char*  w8  = (char*)d_ws;

    // workspace (byte offsets, aliased by lifetime):
    __hip_bfloat16* qbf    = (__hip_bfloat16*)(w8 + 0);          // q_full bf16
    __hip_bfloat16* yprebf = (__hip_bfloat16*)(w8 + 67108864);   // y_pre bf16
    __hip_bfloat16* hidden = (__hip_bfloat16*)(w8 + 0);          // after q dead
    __hip_bfloat16* xbf    = (__hip_bfloat16*)(w8 + 134217728);  // x/attnout/y
    float*          kf     = (float*)(w8 + 167772160);
    float*          vf     = (float*)(w8 + 169033728);
    float*          qsum   = (float*)(w8 + 170295296);           // 128 KiB
    float*          mskp   = (float*)(w8 + 170428832);
    float*          gate   = (float*)(w8 + 170431296);
    __hip_bfloat16* WqT    = (__hip_bfloat16*)(w8 + 170562368);
    __hip_bfloat16* WoT    = (__hip_bfloat16*)(w8 + 171086656);
    __hip_bfloat16* w1T    = (__hip_bfloat16*)(w8 + 171610944);
    __hip_bfloat16* w2T    = (__hip_bfloat16*)(w8 + 173708096);
    __hip_bfloat16* kbfg   = (__hip_bfloat16*)(w8 + 175805248);  // k-hat bf16

    // 0. all weight transposes in one launch; zero qsum for the atomic fold
    wtrans4_kernel<<<dim3(2560), dim3(256), 0, stream>>>(
        Wq, Wo, w1, w2, WqT, WoT, w1T, w2T);
    hipMemsetAsync(qsum, 0, MROWS * sizeof(float), stream);

    // 1. LN1: x -> d_out (f32 residual) + xbf (bf16); gate logits
    ln_kernel<true, true, false><<<dim3(MROWS), dim3(128), 0, stream>>>(
        visual, n1w, n1b, out, xbf, gw, gb, gate);

    // 2. q_full = x @ Wq + bq -> bf16 + folded row sum-of-squares (qsum)
    bgemm_kernel<16, EPI_QBF><<<dim3(1024), dim3(256), 0, stream>>>(
        xbf, WqT, bq, qbf, MROWS, 512, qsum, nullptr, nullptr, nullptr);

    // 3. k_full / v_full in one launch (fp32, tiny M=616)
    gemm32kv_kernel<<<dim3(8, 10, 2), dim3(256), 0, stream>>>(
        text, Wk, bk, kf, Wv, bv, vf, KTROWS, 512);

    // 4. k norm + pad mask + pre-normalized bf16 k-hat
    knorm_mask_kernel<<<dim3(KTROWS), dim3(64), 0, stream>>>(kf, text, mskp, kbfg);

    // 5. MFMA attention -> attnout bf16 (reuses xbf buffer; x_bf16 dead)
    attn_kernel<<<dim3(1024), dim3(256), 0, stream>>>(
        qbf, kbfg, vf, qsum, mskp, lsc, xbf);

    // 6. y_pre = x + alpha*gate*(attnout @ Wo + bo) -> bf16 (r17)
    bgemm_kernel<16, EPI_WO><<<dim3(1024), dim3(256), 0, stream>>>(
        xbf, WoT, bo, yprebf, MROWS, 512, out, gate, alp, nullptr);

    // 7. y = LN2(y_pre bf16) -> bf16 (residual for FFN2 read as bf16)
    ln_kernel<false, false, true><<<dim3(MROWS), dim3(128), 0, stream>>>(
        yprebf, n2w, n2b, nullptr, xbf, nullptr, nullptr, nullptr);

    // 8. hidden = gelu(y @ w1 + b1) -> bf16; 128^2 tile (r15-verified config)
    bgemm_kernel<16, EPI_GELU><<<dim3(4096), dim3(256), 0, stream>>>(
        xbf, w1T, b1, hidden, MROWS, 2048, nullptr, nullptr, nullptr, nullptr);

    // 9. out = bf16(y) + hidden @ w2 + b2; y-residual from xbf (bf16)
    bgemm_kernel<64, EPI_RES><<<dim3(1024), dim3(256), 0, stream>>>(
        hidden, w2T, b2, out, MROWS, 512, nullptr, nullptr, nullptr, xbf);
}